// Round 1
// baseline (395.054 us; speedup 1.0000x reference)
//
#include <hip/hip_runtime.h>
#include <hip/hip_bf16.h>

// CrossNetMix: B=16384, D=1024, R=64, E=4, L=3
// Per layer (row-local!):  g = softmax(xl @ Gw^T)            [B,4]
//   h  = tanh(xl @ V^T)                                      [B,256]   (V as [256,1024])
//   t2 = tanh(C @ h)  per expert                             [B,256]
//   w  = g_e * t2                                            [B,256]
//   xl += x0 * (bias + w @ Umat)   where Umat[e*64+r][d] = U[e][d][r]
// (uses sum_e g_e == 1 to fold bias)

using bf16x8 = __attribute__((ext_vector_type(8))) short;
using f32x4  = __attribute__((ext_vector_type(4))) float;

__device__ __forceinline__ unsigned short f2bf(float f) {
  union { __hip_bfloat16 h; unsigned short s; } u;
  u.h = __float2bfloat16(f);   // RNE
  return u.s;
}
__device__ __forceinline__ unsigned int pk2(float a, float b) {
  return (unsigned int)f2bf(a) | ((unsigned int)f2bf(b) << 16);
}
__device__ __forceinline__ float fast_tanh(float x) {
  float cx = fminf(15.0f, fmaxf(-15.0f, x));
  float t = exp2f(cx * 2.885390081777927f);   // e^(2x)
  return (t - 1.0f) / (t + 1.0f);
}

// ---- convert fp32 weights -> bf16 workspace (runs every call; deterministic)
__global__ void preconvert_k(const float* __restrict__ U, const float* __restrict__ V,
                             const float* __restrict__ C, const float* __restrict__ G,
                             unsigned short* __restrict__ Vb, unsigned short* __restrict__ Ub,
                             unsigned short* __restrict__ Cb, unsigned short* __restrict__ Gb) {
  int i = blockIdx.x * 256 + threadIdx.x;
  if (i < 786432) { Vb[i] = f2bf(V[i]); Ub[i] = f2bf(U[i]); }  // L*E*R*D == L*E*D*R
  if (i < 49152)  Cb[i] = f2bf(C[i]);                          // L*E*R*R
  if (i < 4096)   Gb[i] = f2bf(G[i]);                          // E*D
}

// ---- one layer, BM=64 rows per block, 8 waves (512 thr)
__global__ __launch_bounds__(512, 2)
void crossmix_layer(const float* xl_in, float* xl_out, const float* x0,
                    const unsigned short* __restrict__ Vb,   // [256][1024]
                    const unsigned short* __restrict__ Ub,   // [E][D][R]
                    const unsigned short* __restrict__ Cb,   // [E][R][R]
                    const unsigned short* __restrict__ Gb,   // [E][D]
                    const float* __restrict__ bias) {        // [D]
  constexpr int BM = 64, DD = 1024, BK = 128;
  __shared__ unsigned short xlbuf[2][BM * BK];   // 2x16KB, XOR-swizzled bf16 xl chunks
  __shared__ unsigned short tbuf[BM * 256];      // 32KB, swizzled; holds t then w
  __shared__ float g_lds[BM][4];                 // gate logits -> softmax g

  const int tid  = threadIdx.x;
  const int lane = tid & 63;
  const int wave = tid >> 6;          // 0..7
  const int l15  = lane & 15;
  const int l4   = lane >> 4;         // 0..3
  const int rowbase = blockIdx.x * BM;

  // -------- staging (split issue/write so HBM/L2 latency hides under MFMAs)
  float4 sv[4];
  auto stage_load = [&](int c) {
    int r = tid >> 3, cb = (tid & 7) * 16;
    const float* s = xl_in + (size_t)(rowbase + r) * DD + c * BK + cb;
    sv[0] = *(const float4*)(s);
    sv[1] = *(const float4*)(s + 4);
    sv[2] = *(const float4*)(s + 8);
    sv[3] = *(const float4*)(s + 12);
  };
  auto stage_write = [&](int buf) {
    int r = tid >> 3, cb = (tid & 7) * 16;
    uint4 p0 = make_uint4(pk2(sv[0].x, sv[0].y), pk2(sv[0].z, sv[0].w),
                          pk2(sv[1].x, sv[1].y), pk2(sv[1].z, sv[1].w));
    uint4 p1 = make_uint4(pk2(sv[2].x, sv[2].y), pk2(sv[2].z, sv[2].w),
                          pk2(sv[3].x, sv[3].y), pk2(sv[3].z, sv[3].w));
    char* lb = (char*)xlbuf[buf];
    int base = r * 256 + cb * 2;
    int swz  = (r & 7) << 4;
    *(uint4*)(lb + ((base)      ^ swz)) = p0;
    *(uint4*)(lb + ((base + 16) ^ swz)) = p1;
  };

  // ================= G1: h = xl @ V^T  (+ gate logits on wave 0) ==========
  f32x4 zf = {0.f, 0.f, 0.f, 0.f};
  f32x4 acc1[4][2], accg[4];
  #pragma unroll
  for (int m = 0; m < 4; ++m) { acc1[m][0] = zf; acc1[m][1] = zf; accg[m] = zf; }
  const int ncol = wave * 32;   // this wave's G1 output columns (er-space)

  stage_load(0); stage_write(0);
  __syncthreads();
  for (int c = 0; c < 8; ++c) {
    if (c < 7) stage_load(c + 1);          // issue loads early
    const char* lb = (const char*)xlbuf[c & 1];
    #pragma unroll
    for (int ki = 0; ki < 4; ++ki) {
      bf16x8 afr[4];
      #pragma unroll
      for (int mt = 0; mt < 4; ++mt) {
        int row = mt * 16 + l15;
        afr[mt] = *(const bf16x8*)(lb + ((row * 256 + ki * 64 + l4 * 16) ^ ((row & 7) << 4)));
      }
      int kg = c * 128 + ki * 32 + l4 * 8;
      #pragma unroll
      for (int nt = 0; nt < 2; ++nt) {
        bf16x8 bfr = *(const bf16x8*)(Vb + (ncol + nt * 16 + l15) * 1024 + kg);
        #pragma unroll
        for (int mt = 0; mt < 4; ++mt)
          acc1[mt][nt] = __builtin_amdgcn_mfma_f32_16x16x32_bf16(afr[mt], bfr, acc1[mt][nt], 0, 0, 0);
      }
      if (wave == 0) {   // gate logits as an extra N-tile (cols 0..3 real, rest zero)
        bf16x8 gfr = {0, 0, 0, 0, 0, 0, 0, 0};
        if (l15 < 4) gfr = *(const bf16x8*)(Gb + l15 * 1024 + kg);
        #pragma unroll
        for (int mt = 0; mt < 4; ++mt)
          accg[mt] = __builtin_amdgcn_mfma_f32_16x16x32_bf16(afr[mt], gfr, accg[mt], 0, 0, 0);
      }
    }
    if (c < 7) stage_write((c + 1) & 1);   // cvt+LDS write after compute
    __syncthreads();
  }

  // gate logits -> LDS ; t = tanh(h) -> tbuf (swizzled)
  if (wave == 0 && l15 < 4) {
    #pragma unroll
    for (int mt = 0; mt < 4; ++mt)
      #pragma unroll
      for (int rg = 0; rg < 4; ++rg)
        g_lds[mt * 16 + l4 * 4 + rg][l15] = accg[mt][rg];
  }
  #pragma unroll
  for (int mt = 0; mt < 4; ++mt)
    #pragma unroll
    for (int nt = 0; nt < 2; ++nt) {
      int col = ncol + nt * 16 + l15;
      #pragma unroll
      for (int rg = 0; rg < 4; ++rg) {
        int row = mt * 16 + l4 * 4 + rg;
        *(unsigned short*)((char*)tbuf + ((row * 512 + col * 2) ^ ((row & 7) << 4)))
            = f2bf(fast_tanh(acc1[mt][nt][rg]));
      }
    }
  __syncthreads();

  // softmax over 4 experts, one thread per row
  if (tid < BM) {
    float a0 = g_lds[tid][0], a1 = g_lds[tid][1], a2 = g_lds[tid][2], a3 = g_lds[tid][3];
    float mx = fmaxf(fmaxf(a0, a1), fmaxf(a2, a3));
    float e0 = exp2f((a0 - mx) * 1.442695041f);
    float e1 = exp2f((a1 - mx) * 1.442695041f);
    float e2 = exp2f((a2 - mx) * 1.442695041f);
    float e3 = exp2f((a3 - mx) * 1.442695041f);
    float inv = 1.0f / (e0 + e1 + e2 + e3);
    g_lds[tid][0] = e0 * inv; g_lds[tid][1] = e1 * inv;
    g_lds[tid][2] = e2 * inv; g_lds[tid][3] = e3 * inv;
  }
  __syncthreads();

  // ================= C-mix: t2 = tanh(C@t); w = g*t2 -> tbuf ==============
  const int ex  = wave >> 1;          // expert owned by this wave pair
  const int cb2 = (wave & 1) * 32;    // column half within expert
  f32x4 acc2[4][2];
  #pragma unroll
  for (int m = 0; m < 4; ++m) { acc2[m][0] = zf; acc2[m][1] = zf; }
  #pragma unroll
  for (int ki = 0; ki < 2; ++ki) {
    bf16x8 afr[4];
    #pragma unroll
    for (int mt = 0; mt < 4; ++mt) {
      int row = mt * 16 + l15;
      int kcol = ex * 64 + ki * 32 + l4 * 8;
      afr[mt] = *(const bf16x8*)((const char*)tbuf + ((row * 512 + kcol * 2) ^ ((row & 7) << 4)));
    }
    #pragma unroll
    for (int nt = 0; nt < 2; ++nt) {
      int rr = cb2 + nt * 16 + l15;
      bf16x8 bfr = *(const bf16x8*)(Cb + ex * 4096 + rr * 64 + ki * 32 + l4 * 8);
      #pragma unroll
      for (int mt = 0; mt < 4; ++mt)
        acc2[mt][nt] = __builtin_amdgcn_mfma_f32_16x16x32_bf16(afr[mt], bfr, acc2[mt][nt], 0, 0, 0);
    }
  }
  __syncthreads();   // all reads of t done before overwriting tbuf with w
  #pragma unroll
  for (int mt = 0; mt < 4; ++mt)
    #pragma unroll
    for (int nt = 0; nt < 2; ++nt) {
      int col = ex * 64 + cb2 + nt * 16 + l15;
      #pragma unroll
      for (int rg = 0; rg < 4; ++rg) {
        int row = mt * 16 + l4 * 4 + rg;
        float gv = g_lds[row][ex];
        *(unsigned short*)((char*)tbuf + ((row * 512 + col * 2) ^ ((row & 7) << 4)))
            = f2bf(gv * fast_tanh(acc2[mt][nt][rg]));
      }
    }
  __syncthreads();

  // ================= G2: delta = w @ Umat ; epilogue ======================
  // two 512-col phases to keep acc at 64 VGPRs
  #pragma unroll 1
  for (int ph = 0; ph < 2; ++ph) {
    f32x4 acc3[4][4];
    #pragma unroll
    for (int m = 0; m < 4; ++m)
      #pragma unroll
      for (int n = 0; n < 4; ++n) acc3[m][n] = zf;
    #pragma unroll 2
    for (int ki = 0; ki < 8; ++ki) {
      bf16x8 afr[4];
      #pragma unroll
      for (int mt = 0; mt < 4; ++mt) {
        int row = mt * 16 + l15;
        afr[mt] = *(const bf16x8*)((const char*)tbuf +
                   ((row * 512 + (ki * 32 + l4 * 8) * 2) ^ ((row & 7) << 4)));
      }
      int k = ki * 32 + l4 * 8;
      int ee = k >> 6, rr = k & 63;
      #pragma unroll
      for (int nt = 0; nt < 4; ++nt) {
        int d = ph * 512 + wave * 64 + nt * 16 + l15;
        bf16x8 bfr = *(const bf16x8*)(Ub + ee * 65536 + d * 64 + rr);  // U[e][d][r]
        #pragma unroll
        for (int mt = 0; mt < 4; ++mt)
          acc3[mt][nt] = __builtin_amdgcn_mfma_f32_16x16x32_bf16(afr[mt], bfr, acc3[mt][nt], 0, 0, 0);
      }
    }
    // epilogue: xl_out = xl_in + x0*(bias + delta)   (f32 residual path)
    #pragma unroll
    for (int nt = 0; nt < 4; ++nt) {
      int d = ph * 512 + wave * 64 + nt * 16 + l15;
      float bv = bias[d];
      #pragma unroll
      for (int mt = 0; mt < 4; ++mt)
        #pragma unroll
        for (int rg = 0; rg < 4; ++rg) {
          size_t idx = (size_t)(rowbase + mt * 16 + l4 * 4 + rg) * DD + d;
          xl_out[idx] = xl_in[idx] + x0[idx] * (bv + acc3[mt][nt][rg]);
        }
    }
  }
}

extern "C" void kernel_launch(void* const* d_in, const int* in_sizes, int n_in,
                              void* d_out, int out_size, void* d_ws, size_t ws_size,
                              hipStream_t stream) {
  const float* x    = (const float*)d_in[0];   // [B,D]
  const float* U    = (const float*)d_in[1];   // [L,E,D,R]
  const float* V    = (const float*)d_in[2];   // [L,E,R,D]
  const float* C    = (const float*)d_in[3];   // [L,E,R,R]
  const float* bias = (const float*)d_in[4];   // [L,D]
  const float* gw   = (const float*)d_in[5];   // [E,D]
  float* out = (float*)d_out;

  // ws: bf16 weights only (~3.25 MB)
  unsigned short* Vb = (unsigned short*)d_ws;  // 786432
  unsigned short* Ub = Vb + 786432;            // 786432
  unsigned short* Cb = Ub + 786432;            // 49152
  unsigned short* Gb = Cb + 49152;             // 4096

  preconvert_k<<<dim3(3072), dim3(256), 0, stream>>>(U, V, C, gw, Vb, Ub, Cb, Gb);

  // layer 0: x -> out ; layers 1,2: out -> out (in-place is safe: row-local)
  for (int l = 0; l < 3; ++l) {
    const float* xin = (l == 0) ? x : out;
    crossmix_layer<<<dim3(256), dim3(512), 0, stream>>>(
        xin, out, x,
        Vb + l * 262144, Ub + l * 262144, Cb + l * 16384, Gb,
        bias + l * 1024);
  }
}